// Round 8
// baseline (28.712 us; speedup 1.0000x reference)
//
#include <hip/hip_runtime.h>
#include <math.h>

// Focal-weighted BCE-with-logits, mean-reduced. TWO kernels, plain memory.
//
// Round-8 structure: block-cooperative LDS transpose staging. The old
// per-thread layout made every pred load a 48B-lane-stride dwordx4 (~48
// cache lines/instr, 3x the minimum transactions). Now: 3 UNIT-STRIDE
// staging loads/thread -> padded LDS (13 words/group; 13 coprime 32 =>
// conflict-free) -> each thread reads its group's 12 contiguous words.
// targ int4 load was already unit-stride. Exactly 1 iteration per block.
//
// col = targ==1 ? 0 : targ==3 ? 1 : 2 ; t = onehot(col)
// w   = t ? (1-x)^2 : x^2
// bce = max(x,0) - x*t + log1p(exp(-|x|))
// out = mean(w * bce)

#define GRID   8192
#define BLOCK  256
#define FBLOCK 1024
#define GPB    256                      // groups per block (= BLOCK)
#define LDS_STRIDE 13                   // words per group (12 + 1 pad)

typedef float f32x4 __attribute__((ext_vector_type(4)));
typedef int   i32x4 __attribute__((ext_vector_type(4)));

__device__ __forceinline__ float elem_loss(float x, bool is_t) {
    float l   = __logf(1.0f + __expf(-fabsf(x)));        // log1p(exp(-|x|))
    float bce = fmaxf(x, 0.0f) + l - (is_t ? x : 0.0f);
    float m   = is_t ? (1.0f - x) : x;                   // 1 - pt
    return m * m * bce;
}

__device__ __forceinline__ float group_loss12(const float* f, i32x4 tg) {
    int tt[4] = {tg.x, tg.y, tg.z, tg.w};
    float acc = 0.0f;
    #pragma unroll
    for (int a = 0; a < 4; ++a) {
        int col = (tt[a] == 1) ? 0 : ((tt[a] == 3) ? 1 : 2);
        #pragma unroll
        for (int j = 0; j < 3; ++j)
            acc += elem_loss(f[a * 3 + j], j == col);
    }
    return acc;
}

__global__ __launch_bounds__(BLOCK) void focal_partial(
        const float* __restrict__ pred,
        const int*   __restrict__ targ,
        float*       __restrict__ partial,
        int n_anchors) {
    __shared__ float lds[LDS_STRIDE * GPB];              // 13312 B

    const int t            = threadIdx.x;
    const int groups_total = n_anchors >> 2;
    const int main_groups  = GRID * GPB;

    const f32x4* __restrict__ p4 = (const f32x4*)pred;
    const i32x4* __restrict__ t4 = (const i32x4*)targ;

    float acc = 0.0f;

    const int gbase = blockIdx.x * GPB;                  // this block's first group
    if (gbase + GPB <= groups_total) {
        // ---- cooperative path (always taken at bench sizes) ----
        const int pbase = blockIdx.x * (3 * GPB);        // f32x4 base (fits int: <6.3M)
        f32x4 s0 = p4[pbase + t];                        // 3 unit-stride staging loads
        f32x4 s1 = p4[pbase + 256 + t];
        f32x4 s2 = p4[pbase + 512 + t];
        i32x4 tg = t4[gbase + t];                        // unit-stride, issues early

        // scatter to padded LDS: flat f32x4 u -> group u/3, word 4*(u%3)
        #pragma unroll
        for (int k = 0; k < 3; ++k) {
            const int u = 256 * k + t;
            const int q = u / 3;
            const int r = u - 3 * q;
            float* dst = &lds[LDS_STRIDE * q + 4 * r];
            f32x4 v = (k == 0) ? s0 : ((k == 1) ? s1 : s2);
            dst[0] = v.x; dst[1] = v.y; dst[2] = v.z; dst[3] = v.w;
        }
        __syncthreads();

        float f[12];
        #pragma unroll
        for (int j = 0; j < 12; ++j)
            f[j] = lds[LDS_STRIDE * t + j];              // 13t+j: 2-way max, free
        acc += group_loss12(f, tg);
    } else {
        // partial last block (not hit at bench sizes): direct strided path
        for (int g = gbase + t; g < groups_total; g += BLOCK) {
            f32x4 f0 = p4[3 * g + 0];
            f32x4 f1 = p4[3 * g + 1];
            f32x4 f2 = p4[3 * g + 2];
            i32x4 tg = t4[g];
            float f[12] = {f0.x, f0.y, f0.z, f0.w,
                           f1.x, f1.y, f1.z, f1.w,
                           f2.x, f2.y, f2.z, f2.w};
            acc += group_loss12(f, tg);
        }
    }

    // groups beyond cooperative coverage (none at bench sizes)
    const int gtid = blockIdx.x * BLOCK + t;
    for (int g = main_groups + gtid; g < groups_total; g += GRID * BLOCK) {
        f32x4 f0 = p4[3 * g + 0];
        f32x4 f1 = p4[3 * g + 1];
        f32x4 f2 = p4[3 * g + 2];
        i32x4 tg = t4[g];
        float f[12] = {f0.x, f0.y, f0.z, f0.w,
                       f1.x, f1.y, f1.z, f1.w,
                       f2.x, f2.y, f2.z, f2.w};
        acc += group_loss12(f, tg);
    }
    // scalar anchor tail (none at bench sizes)
    for (int i = (groups_total << 2) + gtid; i < n_anchors; i += GRID * BLOCK) {
        int tv  = targ[i];
        int col = (tv == 1) ? 0 : ((tv == 3) ? 1 : 2);
        #pragma unroll
        for (int j = 0; j < 3; ++j)
            acc += elem_loss(pred[i * 3 + j], j == col);
    }

    // wave-64 shuffle reduce, then LDS across 4 waves
    #pragma unroll
    for (int off = 32; off; off >>= 1)
        acc += __shfl_down(acc, off, 64);

    __shared__ float sm[4];
    const int lane = t & 63;
    const int wave = t >> 6;
    if (lane == 0) sm[wave] = acc;
    __syncthreads();

    if (t == 0)
        partial[blockIdx.x] = sm[0] + sm[1] + sm[2] + sm[3];
}

__global__ __launch_bounds__(FBLOCK) void final_reduce(
        const float* __restrict__ partial, int nparts,
        float* __restrict__ out, float inv_total) {
    const f32x4* __restrict__ p4 = (const f32x4*)partial;
    float acc = 0.0f;
    for (int i = threadIdx.x; 4 * i < nparts; i += FBLOCK) {
        f32x4 v = p4[i];                                 // 2 loads/thread at 8192 parts
        acc += (v.x + v.y) + (v.z + v.w);
    }

    #pragma unroll
    for (int off = 32; off; off >>= 1)
        acc += __shfl_down(acc, off, 64);

    __shared__ float sm[FBLOCK / 64];
    const int lane = threadIdx.x & 63;
    const int wave = threadIdx.x >> 6;
    if (lane == 0) sm[wave] = acc;
    __syncthreads();

    if (threadIdx.x == 0) {
        float s = 0.0f;
        #pragma unroll
        for (int w = 0; w < FBLOCK / 64; ++w) s += sm[w];
        out[0] = s * inv_total;
    }
}

extern "C" void kernel_launch(void* const* d_in, const int* in_sizes, int n_in,
                              void* d_out, int out_size, void* d_ws, size_t ws_size,
                              hipStream_t stream) {
    const float* pred = (const float*)d_in[0];
    const int*   targ = (const int*)d_in[1];
    float*       out  = (float*)d_out;
    float*       partial = (float*)d_ws;                 // GRID floats, 16B-aligned

    const int n_anchors = in_sizes[1];
    const float inv_total = 1.0f / (3.0f * (float)n_anchors);

    focal_partial<<<GRID, BLOCK, 0, stream>>>(pred, targ, partial, n_anchors);
    final_reduce<<<1, FBLOCK, 0, stream>>>(partial, GRID, out, inv_total);
}